// Round 1
// baseline (352.072 us; speedup 1.0000x reference)
//
#include <hip/hip_runtime.h>
#include <math.h>

#define F 256
#define TBL 4096
#define SMAX 8.0f
#define EPS 1e-8f

// ---------------------------------------------------------------------------
// k_prep: u[g] = sum_f Wk[f] * Wq[f,g];  c0 = sum_f Wk[f]*bq[f]
// ---------------------------------------------------------------------------
__global__ __launch_bounds__(256)
void k_prep(const float* __restrict__ Wq, const float* __restrict__ bq,
            const float* __restrict__ Wk, float* __restrict__ u,
            float* __restrict__ c0)
{
    __shared__ float wk_s[F];
    __shared__ float red[F];
    int g = threadIdx.x;
    wk_s[g] = Wk[g];
    __syncthreads();
    float acc = 0.f;
    #pragma unroll 4
    for (int f = 0; f < F; ++f)
        acc += wk_s[f] * Wq[f * F + g];      // coalesced across g
    u[g] = acc;

    red[g] = wk_s[g] * bq[g];
    __syncthreads();
    for (int s = 128; s > 0; s >>= 1) {
        if (g < s) red[g] += red[g + s];
        __syncthreads();
    }
    if (g == 0) *c0 = red[0];
}

// ---------------------------------------------------------------------------
// k_main: blocks [0,GA): phase A  -- t[n] = u.x[n]+c0 -> a[n], atomic anorm
//         blocks [GA, GA+TBL/16): build lookup table g(s) (16 rows/block)
// ---------------------------------------------------------------------------
__global__ __launch_bounds__(256)
void k_main(const float* __restrict__ x, const float* __restrict__ E,
            const int* __restrict__ seg, const float* __restrict__ u,
            const float* __restrict__ c0p, const float* __restrict__ Wv,
            const float* __restrict__ W1, const float* __restrict__ b1,
            const float* __restrict__ W2, const float* __restrict__ b2,
            float* __restrict__ a_arr, float* __restrict__ anorm,
            float* __restrict__ table, int N, int GA)
{
    __shared__ float zbuf[16][F];   // 16 KB

    if ((int)blockIdx.x < GA) {
        // ----- phase A: wave per row -----
        const int lane = threadIdx.x & 63;
        const int wid  = threadIdx.x >> 6;
        const int waves_total = GA * 4;
        const float4 u4 = ((const float4*)u)[lane];
        const float c0 = *c0p;
        for (int n = blockIdx.x * 4 + wid; n < N; n += waves_total) {
            const float4 x4 = ((const float4*)(x + (size_t)n * F))[lane];
            float d = x4.x * u4.x + x4.y * u4.y + x4.z * u4.z + x4.w * u4.w;
            #pragma unroll
            for (int off = 32; off; off >>= 1) d += __shfl_xor(d, off);
            if (lane == 0) {
                int b = seg[n];
                float e = fabsf(E[b]);
                float dot = e * (d + c0) * 0.0625f;               // /sqrt(256)
                float a = fmaxf(dot, 0.f) + log1pf(expf(-fabsf(dot)));
                a_arr[n] = a;
                atomicAdd(&anorm[b], a);
            }
        }
    } else {
        // ----- table build: g(s) = s*Wv + h2(s), 16 rows per block -----
        const int tb = blockIdx.x - GA;          // 0 .. TBL/16-1
        const int i  = threadIdx.x;              // feature
        const float delta = SMAX / (float)(TBL - 1);
        const float wv = Wv[i];

        #pragma unroll
        for (int r = 0; r < 16; ++r) {
            float s  = (float)(tb * 16 + r) * delta;
            float zv = s * wv;
            zbuf[r][i] = zv / (1.f + __expf(-zv));               // silu(y)
        }
        __syncthreads();

        float acc[16];
        float bb = b1[i];
        #pragma unroll
        for (int r = 0; r < 16; ++r) acc[r] = bb;
        const float4* w1row = (const float4*)(W1 + (size_t)i * F);
        for (int fc = 0; fc < F / 4; ++fc) {
            float4 w4 = w1row[fc];
            #pragma unroll
            for (int r = 0; r < 16; ++r) {
                float4 z4 = *(const float4*)&zbuf[r][fc * 4];    // wave-uniform broadcast
                acc[r] += w4.x * z4.x + w4.y * z4.y + w4.z * z4.z + w4.w * z4.w;
            }
        }
        __syncthreads();
        #pragma unroll
        for (int r = 0; r < 16; ++r)
            zbuf[r][i] = acc[r] / (1.f + __expf(-acc[r]));       // silu(h1)
        __syncthreads();

        bb = b2[i];
        #pragma unroll
        for (int r = 0; r < 16; ++r) acc[r] = bb;
        const float4* w2row = (const float4*)(W2 + (size_t)i * F);
        for (int fc = 0; fc < F / 4; ++fc) {
            float4 w4 = w2row[fc];
            #pragma unroll
            for (int r = 0; r < 16; ++r) {
                float4 z4 = *(const float4*)&zbuf[r][fc * 4];
                acc[r] += w4.x * z4.x + w4.y * z4.y + w4.z * z4.z + w4.w * z4.w;
            }
        }
        #pragma unroll
        for (int r = 0; r < 16; ++r) {
            float s = (float)(tb * 16 + r) * delta;
            table[(size_t)(tb * 16 + r) * F + i] = s * wv + acc[r];
        }
    }
}

// ---------------------------------------------------------------------------
// k_out: per row n: s = a/(anorm+eps)*|E|;  out[n,:] = lerp(table, s)
// ---------------------------------------------------------------------------
__global__ __launch_bounds__(256)
void k_out(const float* __restrict__ a_arr, const int* __restrict__ seg,
           const float* __restrict__ E, const float* __restrict__ anorm,
           const float* __restrict__ table, float* __restrict__ out, int N)
{
    const int lane = threadIdx.x & 63;
    const int wid  = threadIdx.x >> 6;
    const int waves_total = gridDim.x * 4;
    const float inv_delta = (float)(TBL - 1) / SMAX;
    for (int n = blockIdx.x * 4 + wid; n < N; n += waves_total) {
        int b = seg[n];                       // uniform broadcast loads
        float a = a_arr[n];
        float w = a / (anorm[b] + EPS);
        float s = w * fabsf(E[b]);
        float pos = s * inv_delta;
        int i0 = (int)pos;
        i0 = min(max(i0, 0), TBL - 2);
        float frac = pos - (float)i0;
        const float4 g0 = ((const float4*)(table + (size_t)i0 * F))[lane];
        const float4 g1 = ((const float4*)(table + (size_t)(i0 + 1) * F))[lane];
        float4 o;
        o.x = g0.x + frac * (g1.x - g0.x);
        o.y = g0.y + frac * (g1.y - g0.y);
        o.z = g0.z + frac * (g1.z - g0.z);
        o.w = g0.w + frac * (g1.w - g0.w);
        ((float4*)(out + (size_t)n * F))[lane] = o;
    }
}

// ---------------------------------------------------------------------------
extern "C" void kernel_launch(void* const* d_in, const int* in_sizes, int n_in,
                              void* d_out, int out_size, void* d_ws, size_t ws_size,
                              hipStream_t stream)
{
    const float* x   = (const float*)d_in[0];
    const float* E   = (const float*)d_in[1];
    const int*   seg = (const int*)  d_in[2];   // int64 in ref -> int32 on device
    const float* Wq  = (const float*)d_in[4];
    const float* bq  = (const float*)d_in[5];
    const float* Wk  = (const float*)d_in[6];
    const float* Wv  = (const float*)d_in[7];
    const float* W1  = (const float*)d_in[8];
    const float* b1  = (const float*)d_in[9];
    const float* W2  = (const float*)d_in[10];
    const float* b2  = (const float*)d_in[11];

    const int N = in_sizes[0] / F;
    const int B = in_sizes[1];
    float* out = (float*)d_out;

    float* ws    = (float*)d_ws;
    float* table = ws;                          // TBL*F floats (4 MB)
    float* u     = table + (size_t)TBL * F;     // F
    float* c0    = u + F;                       // 1 (padded to 4)
    float* anorm = c0 + 4;                      // B
    float* a_arr = anorm + B;                   // N

    hipMemsetAsync(anorm, 0, (size_t)B * sizeof(float), stream);

    k_prep<<<1, 256, 0, stream>>>(Wq, bq, Wk, u, c0);

    const int GA = 2048;
    k_main<<<GA + TBL / 16, 256, 0, stream>>>(x, E, seg, u, c0, Wv, W1, b1, W2,
                                              b2, a_arr, anorm, table, N, GA);

    k_out<<<2048, 256, 0, stream>>>(a_arr, seg, E, anorm, table, out, N);
}

// Round 3
// 168.970 us; speedup vs baseline: 2.0836x; 2.0836x over previous
//
#include <hip/hip_runtime.h>
#include <math.h>

#define F 256
#define TBL 4096
#define TBLK (TBL / 16)      // 256 table-builder blocks
#define GA 1792              // phase-A blocks (TBLK + GA = 2048 = one residency round)
#define SMAX 8.0f
#define EPS 1e-8f

typedef float f4 __attribute__((ext_vector_type(4)));

__device__ __forceinline__ float softplus_f(float t) {
    return fmaxf(t, 0.f) + log1pf(expf(-fabsf(t)));
}

// ---------------------------------------------------------------------------
// k_prep: u[g] = sum_f Wk[f] * Wq[f,g];  c0 = sum_f Wk[f]*bq[f]
// ---------------------------------------------------------------------------
__global__ __launch_bounds__(256)
void k_prep(const float* __restrict__ Wq, const float* __restrict__ bq,
            const float* __restrict__ Wk, float* __restrict__ u,
            float* __restrict__ c0)
{
    __shared__ float wk_s[F];
    __shared__ float red[F];
    int g = threadIdx.x;
    wk_s[g] = Wk[g];
    __syncthreads();
    float acc = 0.f;
    #pragma unroll 4
    for (int f = 0; f < F; ++f)
        acc += wk_s[f] * Wq[f * F + g];
    u[g] = acc;

    red[g] = wk_s[g] * bq[g];
    __syncthreads();
    for (int s = 128; s > 0; s >>= 1) {
        if (g < s) red[g] += red[g + s];
        __syncthreads();
    }
    if (g == 0) *c0 = red[0];
}

// ---------------------------------------------------------------------------
// k_main: blocks [0,TBLK): build lookup table g(s) (16 rows/block)
//         blocks [TBLK, TBLK+GA): phase A — a[n] = softplus(.), anorm seg-sum
// ---------------------------------------------------------------------------
__global__ __launch_bounds__(256)
void k_main(const float* __restrict__ x, const float* __restrict__ E,
            const int* __restrict__ seg, const float* __restrict__ u,
            const float* __restrict__ c0p, const float* __restrict__ Wv,
            const float* __restrict__ W1, const float* __restrict__ b1,
            const float* __restrict__ W2, const float* __restrict__ b2,
            float* __restrict__ a_arr, float* __restrict__ anorm,
            float* __restrict__ table, int N)
{
    __shared__ float zbuf[16][F];   // 16 KB (table blocks only)

    if ((int)blockIdx.x >= TBLK) {
        // ----- phase A: contiguous chunk per wave, 4 rows/iter -----
        const int lane = threadIdx.x & 63;
        const int wid  = threadIdx.x >> 6;
        const int gwave = (blockIdx.x - TBLK) * 4 + wid;
        const int total_waves = GA * 4;
        const int chunk = (N + total_waves - 1) / total_waves;
        const int n0 = gwave * chunk;
        const int n1 = min(n0 + chunk, N);
        if (n0 >= n1) return;

        const f4 u4 = ((const f4*)u)[lane];
        const float c0 = *c0p;

        int   curb = seg[n0];
        float accA = 0.f;

        int n = n0;
        for (; n + 3 < n1; n += 4) {
            const f4* xp = (const f4*)(x + (size_t)n * F) + lane;
            f4 r0 = __builtin_nontemporal_load(xp);
            f4 r1 = __builtin_nontemporal_load(xp + 64);
            f4 r2 = __builtin_nontemporal_load(xp + 128);
            f4 r3 = __builtin_nontemporal_load(xp + 192);
            float d0 = r0.x * u4.x + r0.y * u4.y + r0.z * u4.z + r0.w * u4.w;
            float d1 = r1.x * u4.x + r1.y * u4.y + r1.z * u4.z + r1.w * u4.w;
            float d2 = r2.x * u4.x + r2.y * u4.y + r2.z * u4.z + r2.w * u4.w;
            float d3 = r3.x * u4.x + r3.y * u4.y + r3.z * u4.z + r3.w * u4.w;
            #pragma unroll
            for (int off = 32; off; off >>= 1) {
                d0 += __shfl_xor(d0, off);
                d1 += __shfl_xor(d1, off);
                d2 += __shfl_xor(d2, off);
                d3 += __shfl_xor(d3, off);
            }
            // wave-uniform: seg/E loads (same addr all lanes -> broadcast)
            int b0 = seg[n], b1i = seg[n + 1], b2i = seg[n + 2], b3 = seg[n + 3];
            float a0 = softplus_f(fabsf(E[b0])  * (d0 + c0) * 0.0625f);
            float a1 = softplus_f(fabsf(E[b1i]) * (d1 + c0) * 0.0625f);
            float a2 = softplus_f(fabsf(E[b2i]) * (d2 + c0) * 0.0625f);
            float a3 = softplus_f(fabsf(E[b3])  * (d3 + c0) * 0.0625f);
            float av = (lane == 0) ? a0 : (lane == 1) ? a1 : (lane == 2) ? a2 : a3;
            if (lane < 4) a_arr[n + lane] = av;
            if (lane == 0) {
                if (b0 != curb) { atomicAdd(&anorm[curb], accA); accA = 0.f; curb = b0; }
                accA += a0;
                if (b1i != curb) { atomicAdd(&anorm[curb], accA); accA = 0.f; curb = b1i; }
                accA += a1;
                if (b2i != curb) { atomicAdd(&anorm[curb], accA); accA = 0.f; curb = b2i; }
                accA += a2;
                if (b3 != curb) { atomicAdd(&anorm[curb], accA); accA = 0.f; curb = b3; }
                accA += a3;
            }
        }
        for (; n < n1; ++n) {
            const f4* xp = (const f4*)(x + (size_t)n * F) + lane;
            f4 r0 = __builtin_nontemporal_load(xp);
            float d0 = r0.x * u4.x + r0.y * u4.y + r0.z * u4.z + r0.w * u4.w;
            #pragma unroll
            for (int off = 32; off; off >>= 1) d0 += __shfl_xor(d0, off);
            int b0 = seg[n];
            float a0 = softplus_f(fabsf(E[b0]) * (d0 + c0) * 0.0625f);
            if (lane == 0) {
                a_arr[n] = a0;
                if (b0 != curb) { atomicAdd(&anorm[curb], accA); accA = 0.f; curb = b0; }
                accA += a0;
            }
        }
        if (lane == 0) atomicAdd(&anorm[curb], accA);
    } else {
        // ----- table build: g(s) = s*Wv + h2(s), 16 rows per block -----
        const int tb = blockIdx.x;               // 0 .. TBLK-1
        const int i  = threadIdx.x;              // feature
        const float delta = SMAX / (float)(TBL - 1);
        const float wv = Wv[i];

        #pragma unroll
        for (int r = 0; r < 16; ++r) {
            float s  = (float)(tb * 16 + r) * delta;
            float zv = s * wv;
            zbuf[r][i] = zv / (1.f + __expf(-zv));               // silu(y)
        }
        __syncthreads();

        float acc[16];
        float bb = b1[i];
        #pragma unroll
        for (int r = 0; r < 16; ++r) acc[r] = bb;
        const f4* w1row = (const f4*)(W1 + (size_t)i * F);
        for (int fc = 0; fc < F / 4; ++fc) {
            f4 w4 = w1row[fc];
            #pragma unroll
            for (int r = 0; r < 16; ++r) {
                f4 z4 = *(const f4*)&zbuf[r][fc * 4];    // uniform broadcast
                acc[r] += w4.x * z4.x + w4.y * z4.y + w4.z * z4.z + w4.w * z4.w;
            }
        }
        __syncthreads();
        #pragma unroll
        for (int r = 0; r < 16; ++r)
            zbuf[r][i] = acc[r] / (1.f + __expf(-acc[r]));       // silu(h1)
        __syncthreads();

        bb = b2[i];
        #pragma unroll
        for (int r = 0; r < 16; ++r) acc[r] = bb;
        const f4* w2row = (const f4*)(W2 + (size_t)i * F);
        for (int fc = 0; fc < F / 4; ++fc) {
            f4 w4 = w2row[fc];
            #pragma unroll
            for (int r = 0; r < 16; ++r) {
                f4 z4 = *(const f4*)&zbuf[r][fc * 4];
                acc[r] += w4.x * z4.x + w4.y * z4.y + w4.z * z4.z + w4.w * z4.w;
            }
        }
        #pragma unroll
        for (int r = 0; r < 16; ++r) {
            float s = (float)(tb * 16 + r) * delta;
            table[(size_t)(tb * 16 + r) * F + i] = s * wv + acc[r];
        }
    }
}

// ---------------------------------------------------------------------------
// k_out: per row n: s = a/(anorm+eps)*|E|;  out[n,:] = lerp(table, s)
// ---------------------------------------------------------------------------
__global__ __launch_bounds__(256)
void k_out(const float* __restrict__ a_arr, const int* __restrict__ seg,
           const float* __restrict__ E, const float* __restrict__ anorm,
           const float* __restrict__ table, float* __restrict__ out, int N)
{
    const int lane = threadIdx.x & 63;
    const int wid  = threadIdx.x >> 6;
    const int waves_total = gridDim.x * 4;
    const float inv_delta = (float)(TBL - 1) / SMAX;
    for (int n = blockIdx.x * 4 + wid; n < N; n += waves_total) {
        int b = seg[n];                       // uniform broadcast loads
        float a = a_arr[n];
        float w = a / (anorm[b] + EPS);
        float s = w * fabsf(E[b]);
        float pos = s * inv_delta;
        int i0 = (int)pos;
        i0 = min(max(i0, 0), TBL - 2);
        float frac = pos - (float)i0;
        const f4 g0 = ((const f4*)(table + (size_t)i0 * F))[lane];
        const f4 g1 = ((const f4*)(table + (size_t)(i0 + 1) * F))[lane];
        f4 o;
        o.x = g0.x + frac * (g1.x - g0.x);
        o.y = g0.y + frac * (g1.y - g0.y);
        o.z = g0.z + frac * (g1.z - g0.z);
        o.w = g0.w + frac * (g1.w - g0.w);
        __builtin_nontemporal_store(o, (f4*)(out + (size_t)n * F) + lane);
    }
}

// ---------------------------------------------------------------------------
extern "C" void kernel_launch(void* const* d_in, const int* in_sizes, int n_in,
                              void* d_out, int out_size, void* d_ws, size_t ws_size,
                              hipStream_t stream)
{
    const float* x   = (const float*)d_in[0];
    const float* E   = (const float*)d_in[1];
    const int*   seg = (const int*)  d_in[2];
    const float* Wq  = (const float*)d_in[4];
    const float* bq  = (const float*)d_in[5];
    const float* Wk  = (const float*)d_in[6];
    const float* Wv  = (const float*)d_in[7];
    const float* W1  = (const float*)d_in[8];
    const float* b1  = (const float*)d_in[9];
    const float* W2  = (const float*)d_in[10];
    const float* b2  = (const float*)d_in[11];

    const int N = in_sizes[0] / F;
    const int B = in_sizes[1];
    float* out = (float*)d_out;

    float* ws    = (float*)d_ws;
    float* table = ws;                          // TBL*F floats (4 MB)
    float* u     = table + (size_t)TBL * F;     // F
    float* c0    = u + F;                       // 1 (padded to 4)
    float* anorm = c0 + 4;                      // B
    float* a_arr = anorm + B;                   // N

    (void)hipMemsetAsync(anorm, 0, (size_t)B * sizeof(float), stream);

    k_prep<<<1, 256, 0, stream>>>(Wq, bq, Wk, u, c0);

    k_main<<<TBLK + GA, 256, 0, stream>>>(x, E, seg, u, c0, Wv, W1, b1, W2,
                                          b2, a_arr, anorm, table, N);

    k_out<<<2048, 256, 0, stream>>>(a_arr, seg, E, anorm, table, out, N);
}